// Round 15
// baseline (1009.758 us; speedup 1.0000x reference)
//
#include <hip/hip_runtime.h>

// ---------------------------------------------------------------------------
// LlamaDecoderLayer forward on MI355X (gfx950).
// B=4, L=1024, D=2048, H=16, I=8192, DH=128.
// Outputs (f32): out (B,L,D) then attn (B,H,L,L), concatenated in d_out.
// ---------------------------------------------------------------------------

typedef __bf16 bf16;
typedef __bf16 bf16x8 __attribute__((ext_vector_type(8)));
typedef __bf16 bf16x4 __attribute__((ext_vector_type(4)));
typedef float  f32x4  __attribute__((ext_vector_type(4)));

constexpr int   kB  = 4;
constexpr int   kL  = 1024;
constexpr int   kD  = 2048;
constexpr int   kH  = 16;
constexpr int   kI  = 8192;
constexpr int   kDH = 128;
constexpr int   kQKV = 3 * kD;  // 6144
constexpr float kEps = 1e-6f;
constexpr float kScoreScale = 0.08838834764831845f; // 1/sqrt(128)

typedef __attribute__((address_space(1))) void gvoid_t;
typedef __attribute__((address_space(3))) void lvoid_t;

__device__ __forceinline__ void gload_lds16(const void* g, void* l) {
  __builtin_amdgcn_global_load_lds((gvoid_t*)g, (lvoid_t*)l, 16, 0, 0);
}

#define ASM_VMCNT(n) asm volatile("s_waitcnt vmcnt(" #n ")" ::: "memory")

__device__ __forceinline__ void bar_raw() {
  asm volatile("" ::: "memory");
  __builtin_amdgcn_s_barrier();
  asm volatile("" ::: "memory");
}

// ---------------------------------------------------------------------------
// f32 -> bf16 cast (vectorized). n must be a multiple of 4.
// ---------------------------------------------------------------------------
__global__ __launch_bounds__(256) void cast_f32_bf16_kernel(
    const float* __restrict__ x, bf16* __restrict__ y, long n) {
  long i = ((long)blockIdx.x * 256 + threadIdx.x) * 4;
  long stride = (long)gridDim.x * 256 * 4;
  for (; i < n; i += stride) {
    const float4 v = *reinterpret_cast<const float4*>(x + i);
    bf16x4 o;
    o[0] = (bf16)v.x; o[1] = (bf16)v.y; o[2] = (bf16)v.z; o[3] = (bf16)v.w;
    *reinterpret_cast<bf16x4*>(y + i) = o;
  }
}

// ---------------------------------------------------------------------------
// out[i] += p[i] (f32, vectorized), n multiple of 4.
// ---------------------------------------------------------------------------
__global__ __launch_bounds__(256) void add_inplace_kernel(
    float* __restrict__ o, const float* __restrict__ p, long n) {
  long i = ((long)blockIdx.x * 256 + threadIdx.x) * 4;
  const long stride = (long)gridDim.x * 1024;
  for (; i < n; i += stride) {
    float4 a = *(float4*)(o + i);
    const float4 b = *(const float4*)(p + i);
    a.x += b.x; a.y += b.y; a.z += b.z; a.w += b.w;
    *(float4*)(o + i) = a;
  }
}

// ---------------------------------------------------------------------------
// RMSNorm: one block per row of D=2048 f32; writes bf16 (row stride kD).
// ---------------------------------------------------------------------------
__global__ __launch_bounds__(256) void rmsnorm_kernel(
    const float* __restrict__ x, const float* __restrict__ w,
    bf16* __restrict__ out) {
  const long row = blockIdx.x;
  const float* xr = x + row * (long)kD;
  bf16* orow = out + row * (long)kD;
  const int t = threadIdx.x;

  float4 v0 = *(const float4*)(xr + t * 8);
  float4 v1 = *(const float4*)(xr + t * 8 + 4);
  float ss = v0.x * v0.x + v0.y * v0.y + v0.z * v0.z + v0.w * v0.w +
             v1.x * v1.x + v1.y * v1.y + v1.z * v1.z + v1.w * v1.w;

  __shared__ float red[4];
  for (int off = 32; off > 0; off >>= 1) ss += __shfl_down(ss, off);
  if ((t & 63) == 0) red[t >> 6] = ss;
  __syncthreads();
  const float tot = red[0] + red[1] + red[2] + red[3];
  const float rs = rsqrtf(tot / (float)kD + kEps);

  float4 w0 = *(const float4*)(w + t * 8);
  float4 w1 = *(const float4*)(w + t * 8 + 4);
  bf16x8 o;
  o[0] = (bf16)(v0.x * rs * w0.x); o[1] = (bf16)(v0.y * rs * w0.y);
  o[2] = (bf16)(v0.z * rs * w0.z); o[3] = (bf16)(v0.w * rs * w0.w);
  o[4] = (bf16)(v1.x * rs * w1.x); o[5] = (bf16)(v1.y * rs * w1.y);
  o[6] = (bf16)(v1.z * rs * w1.z); o[7] = (bf16)(v1.w * rs * w1.w);
  *(bf16x8*)(orow + t * 8) = o;
}

// ---------------------------------------------------------------------------
// RoPE in-place on qkv buffer (bf16, rows = B*L, ld = 6144).
// ---------------------------------------------------------------------------
__global__ __launch_bounds__(256) void rope_kernel(
    bf16* __restrict__ qkv, const float* __restrict__ cosb,
    const float* __restrict__ sinb) {
  const long row = blockIdx.x;  // b*L + l
  const float* cr = cosb + row * (long)kDH;
  const float* sr = sinb + row * (long)kDH;
  bf16* qr = qkv + row * (long)kQKV;
  bf16* kr = qr + kD;
  const int t = threadIdx.x;
#pragma unroll
  for (int it = 0; it < 4; ++it) {
    const int p = it * 256 + t;  // 0..1023 pair index
    const int h = p >> 6, i = p & 63;
    const int i0 = h * kDH + i, i1 = i0 + 64;
    const float c0 = cr[i], s0 = sr[i], c1 = cr[i + 64], s1 = sr[i + 64];
    const float q0 = (float)qr[i0], q1 = (float)qr[i1];
    qr[i0] = (bf16)(q0 * c0 - q1 * s0);
    qr[i1] = (bf16)(q1 * c1 + q0 * s1);
    const float k0 = (float)kr[i0], k1 = (float)kr[i1];
    kr[i0] = (bf16)(k0 * c0 - k1 * s0);
    kr[i1] = (bf16)(k1 * c1 + k0 * s1);
  }
}

// ---------------------------------------------------------------------------
// v (rows B*L, ld 6144, col offset 4096) -> vT (B,H,DH,L) bf16
// ---------------------------------------------------------------------------
__global__ __launch_bounds__(256) void transpose_v_kernel(
    const bf16* __restrict__ qkv, bf16* __restrict__ vT) {
  __shared__ bf16 tile[32][33];
  const int z = blockIdx.z, b = z / kH, h = z % kH;
  const bf16* src = qkv + (long)b * kL * kQKV + 2 * kD + h * kDH; // [l][d]
  bf16* dst = vT + (long)z * kDH * kL;                            // [d][l]
  const int l0 = blockIdx.x * 32, d0 = blockIdx.y * 32;
  const int tx = threadIdx.x & 31, ty = threadIdx.x >> 5;
  for (int r = ty; r < 32; r += 8)
    tile[r][tx] = src[(long)(l0 + r) * kQKV + d0 + tx];
  __syncthreads();
  for (int r = ty; r < 32; r += 8)
    dst[(long)(d0 + r) * kL + l0 + tx] = tile[tx][r];
}

// ---------------------------------------------------------------------------
// LSE merge: per-row (max, 1/sum) from per-(row, ntile, half) partials.
// ---------------------------------------------------------------------------
__global__ __launch_bounds__(256) void merge_stats_kernel(
    const float2* __restrict__ sp, float2* __restrict__ sm) {
  const int idx = blockIdx.x * 256 + threadIdx.x;  // bh*1024 + row
  const int row = idx & 1023;
  const int n = ((row >> 7) + 1) * 2;
  const float2* p = sp + ((long)idx << 4);
  float M = -3.0e38f;
  for (int i = 0; i < n; ++i) M = fmaxf(M, p[i].x);
  float S = 0.f;
  for (int i = 0; i < n; ++i) S += p[i].y * expf(p[i].x - M);
  sm[idx] = make_float2(M, 1.0f / S);
}

// ---------------------------------------------------------------------------
// 8-PHASE 256x256 GEMM (verified round 11). BK=64, 512 thr / 8 waves.
// ---------------------------------------------------------------------------
template <int EPI>
__global__ __launch_bounds__(512) void gemm8p(
    const bf16* __restrict__ A, int lda, const bf16* __restrict__ B, int ldb,
    bf16* __restrict__ C, int ldc, const bf16* __restrict__ Ep, int lde,
    int K) {
  __shared__ __align__(16) bf16 ls[2][2][2][128 * 64];
  const int t = threadIdx.x;
  const int m0 = blockIdx.x * 256, n0 = blockIdx.y * 256;  // m fastest
  const int wave = t >> 6, lane = t & 63;
  const int ah = wave >> 2;              // A half this wave consumes
  const int wm = ah * 128;
  const int wn = (wave & 3) * 64;
  const int bh = wn >> 7;                // B half this wave consumes
  const int wnr = wn & 127;              // row base within B half
  const int lr = lane & 15, lg = lane >> 4;

  f32x4 acc[8][4] = {};

  auto stageHalf = [&](int b, int O, int h, int k0) {
    const bf16* S = O ? B : A;
    const int ld = O ? ldb : lda;
    const int base = O ? n0 : m0;
#pragma unroll
    for (int cc = 0; cc < 2; ++cc) {
      const int id = cc * 512 + t;       // 0..1023 16B chunks
      const int row = id >> 3, cS = id & 7;
      const int cG = cS ^ (row & 7);     // inverse swizzle on SOURCE
      gload_lds16(S + (long)(base + h * 128 + row) * ld + k0 + cG * 8,
                  (char*)&ls[b][O][h][0] + id * 16);
    }
  };

  auto lread = [&](int b, int O, int h, int row, int c16) {
    return *(const bf16x8*)((const char*)&ls[b][O][h][0] + row * 128 +
                            ((c16 ^ (row & 7)) << 4));
  };

  const int T = K >> 6;
  stageHalf(0, 0, 0, 0); stageHalf(0, 0, 1, 0);
  stageHalf(0, 1, 0, 0); stageHalf(0, 1, 1, 0);
  stageHalf(1, 1, 0, 64); stageHalf(1, 1, 1, 64);

  bf16x8 bfr[2][4];

  for (int w = 0; w < T; ++w) {
    const int c = w & 1;
    const int k1 = (w + 1) << 6, k2 = (w + 2) << 6;
#pragma unroll
    for (int p = 0; p < 4; ++p) {
      bf16x8 af[2][2];
      if (p == 0) {
        if (w + 1 < T) { ASM_VMCNT(4); } else { ASM_VMCNT(0); }
        bar_raw();  // all waves' staging for window w landed
#pragma unroll
        for (int kk = 0; kk < 2; ++kk)
#pragma unroll
          for (int nf = 0; nf < 4; ++nf)
            bfr[kk][nf] = lread(c, 1, bh, wnr + nf * 16 + lr, kk * 4 + lg);
      }
#pragma unroll
      for (int kk = 0; kk < 2; ++kk)
#pragma unroll
        for (int mf = 0; mf < 2; ++mf)
          af[kk][mf] = lread(c, 0, ah, (2 * p + mf) * 16 + lr, kk * 4 + lg);
      if (p == 0 && w + 1 < T) stageHalf(c ^ 1, 0, 0, k1);
      if (p == 1 && w + 1 < T) stageHalf(c ^ 1, 0, 1, k1);
      if (p == 2 && w + 2 < T) stageHalf(c, 1, 0, k2);
      if (p == 3 && w + 2 < T) stageHalf(c, 1, 1, k2);
      bar_raw();
      asm volatile("s_waitcnt lgkmcnt(0)" ::: "memory");
      __builtin_amdgcn_sched_barrier(0);  // rule #18
      __builtin_amdgcn_s_setprio(1);
#pragma unroll
      for (int kk = 0; kk < 2; ++kk)
#pragma unroll
        for (int mf = 0; mf < 2; ++mf)
#pragma unroll
          for (int nf = 0; nf < 4; ++nf)
            acc[2 * p + mf][nf] = __builtin_amdgcn_mfma_f32_16x16x32_bf16(
                af[kk][mf], bfr[kk][nf], acc[2 * p + mf][nf], 0, 0, 0);
      __builtin_amdgcn_s_setprio(0);
      bar_raw();
    }
  }

#pragma unroll
  for (int mf = 0; mf < 8; ++mf) {
#pragma unroll
    for (int nf = 0; nf < 4; ++nf) {
      const int col = n0 + wn + nf * 16 + lr;
#pragma unroll
      for (int r = 0; r < 4; ++r) {
        const int row = m0 + wm + mf * 16 + lg * 4 + r;
        float val = acc[mf][nf][r];
        if constexpr (EPI == 3) {
          const float g = (float)Ep[(long)row * lde + col];
          val = (g / (1.0f + expf(-g))) * val;
        }
        C[(long)row * ldc + col] = (bf16)val;
      }
    }
  }
}

// ---------------------------------------------------------------------------
// 8-PHASE 256x256 GEMM, f32 out, split-K x2 (down): same verified body.
// z=0: C[idx] = acc + C[idx] (C holds h1); z=1: Part[idx] = acc.
// Grid (M/256, N/256, 2); A,B column-offset by z*K. 256 blocks = 1/CU.
// ---------------------------------------------------------------------------
__global__ __launch_bounds__(512) void gemm8pF(
    const bf16* __restrict__ A, int lda, const bf16* __restrict__ B, int ldb,
    float* __restrict__ C, int ldc, float* __restrict__ Part, int K) {
  __shared__ __align__(16) bf16 ls[2][2][2][128 * 64];
  const int t = threadIdx.x;
  const int m0 = blockIdx.x * 256, n0 = blockIdx.y * 256;  // m fastest
  const long ko = (long)blockIdx.z * K;
  A += ko; B += ko;
  const int wave = t >> 6, lane = t & 63;
  const int ah = wave >> 2;
  const int wm = ah * 128;
  const int wn = (wave & 3) * 64;
  const int bh = wn >> 7;
  const int wnr = wn & 127;
  const int lr = lane & 15, lg = lane >> 4;

  f32x4 acc[8][4] = {};

  auto stageHalf = [&](int b, int O, int h, int k0) {
    const bf16* S = O ? B : A;
    const int ld = O ? ldb : lda;
    const int base = O ? n0 : m0;
#pragma unroll
    for (int cc = 0; cc < 2; ++cc) {
      const int id = cc * 512 + t;
      const int row = id >> 3, cS = id & 7;
      const int cG = cS ^ (row & 7);
      gload_lds16(S + (long)(base + h * 128 + row) * ld + k0 + cG * 8,
                  (char*)&ls[b][O][h][0] + id * 16);
    }
  };
  auto lread = [&](int b, int O, int h, int row, int c16) {
    return *(const bf16x8*)((const char*)&ls[b][O][h][0] + row * 128 +
                            ((c16 ^ (row & 7)) << 4));
  };

  const int T = K >> 6;
  stageHalf(0, 0, 0, 0); stageHalf(0, 0, 1, 0);
  stageHalf(0, 1, 0, 0); stageHalf(0, 1, 1, 0);
  stageHalf(1, 1, 0, 64); stageHalf(1, 1, 1, 64);

  bf16x8 bfr[2][4];
  for (int w = 0; w < T; ++w) {
    const int c = w & 1;
    const int k1 = (w + 1) << 6, k2 = (w + 2) << 6;
#pragma unroll
    for (int p = 0; p < 4; ++p) {
      bf16x8 af[2][2];
      if (p == 0) {
        if (w + 1 < T) { ASM_VMCNT(4); } else { ASM_VMCNT(0); }
        bar_raw();
#pragma unroll
        for (int kk = 0; kk < 2; ++kk)
#pragma unroll
          for (int nf = 0; nf < 4; ++nf)
            bfr[kk][nf] = lread(c, 1, bh, wnr + nf * 16 + lr, kk * 4 + lg);
      }
#pragma unroll
      for (int kk = 0; kk < 2; ++kk)
#pragma unroll
        for (int mf = 0; mf < 2; ++mf)
          af[kk][mf] = lread(c, 0, ah, (2 * p + mf) * 16 + lr, kk * 4 + lg);
      if (p == 0 && w + 1 < T) stageHalf(c ^ 1, 0, 0, k1);
      if (p == 1 && w + 1 < T) stageHalf(c ^ 1, 0, 1, k1);
      if (p == 2 && w + 2 < T) stageHalf(c, 1, 0, k2);
      if (p == 3 && w + 2 < T) stageHalf(c, 1, 1, k2);
      bar_raw();
      asm volatile("s_waitcnt lgkmcnt(0)" ::: "memory");
      __builtin_amdgcn_sched_barrier(0);
      __builtin_amdgcn_s_setprio(1);
#pragma unroll
      for (int kk = 0; kk < 2; ++kk)
#pragma unroll
        for (int mf = 0; mf < 2; ++mf)
#pragma unroll
          for (int nf = 0; nf < 4; ++nf)
            acc[2 * p + mf][nf] = __builtin_amdgcn_mfma_f32_16x16x32_bf16(
                af[kk][mf], bfr[kk][nf], acc[2 * p + mf][nf], 0, 0, 0);
      __builtin_amdgcn_s_setprio(0);
      bar_raw();
    }
  }

  const bool z0 = (blockIdx.z == 0);
#pragma unroll
  for (int mf = 0; mf < 8; ++mf) {
#pragma unroll
    for (int nf = 0; nf < 4; ++nf) {
      const int col = n0 + wn + nf * 16 + lr;
#pragma unroll
      for (int r = 0; r < 4; ++r) {
        const int row = m0 + wm + mf * 16 + lg * 4 + r;
        const long idx = (long)row * ldc + col;
        if (z0) C[idx] = acc[mf][nf][r] + C[idx];
        else    Part[idx] = acc[mf][nf][r];
      }
    }
  }
}

// ---------------------------------------------------------------------------
// 2-PHASE-PER-WINDOW 256x128 GEMM, f32 output (oproj; grid 16x16).
// 2 fat phases/window (16 MFMA each). EPIF: 1 = +E (oproj).
// ---------------------------------------------------------------------------
template <int EPIF>
__global__ __launch_bounds__(512) void gemm8pN128(
    const bf16* __restrict__ A, int lda, const bf16* __restrict__ B, int ldb,
    float* __restrict__ C, int ldc, const float* __restrict__ Ef, int lde,
    int K) {
  __shared__ __align__(16) bf16 lsA[2][2][128 * 64];
  __shared__ __align__(16) bf16 lsB[2][128 * 64];
  const int t = threadIdx.x;
  const int m0 = blockIdx.x * 256, n0 = blockIdx.y * 128;  // m fastest
  const int wave = t >> 6, lane = t & 63;
  const int ah = wave >> 2;
  const int wm = ah * 128;
  const int wn = (wave & 3) * 32;
  const int lr = lane & 15, lg = lane >> 4;

  f32x4 acc[8][2] = {};

  auto stageA = [&](int b, int h, int k0) {
#pragma unroll
    for (int cc = 0; cc < 2; ++cc) {
      const int id = cc * 512 + t;
      const int row = id >> 3, cS = id & 7;
      const int cG = cS ^ (row & 7);
      gload_lds16(A + (long)(m0 + h * 128 + row) * lda + k0 + cG * 8,
                  (char*)&lsA[b][h][0] + id * 16);
    }
  };
  auto stageB = [&](int b, int k0) {
#pragma unroll
    for (int cc = 0; cc < 2; ++cc) {
      const int id = cc * 512 + t;
      const int row = id >> 3, cS = id & 7;
      const int cG = cS ^ (row & 7);
      gload_lds16(B + (long)(n0 + row) * ldb + k0 + cG * 8,
                  (char*)&lsB[b][0] + id * 16);
    }
  };
  auto lreadA = [&](int b, int h, int row, int c16) {
    return *(const bf16x8*)((const char*)&lsA[b][h][0] + row * 128 +
                            ((c16 ^ (row & 7)) << 4));
  };
  auto lreadB = [&](int b, int row, int c16) {
    return *(const bf16x8*)((const char*)&lsB[b][0] + row * 128 +
                            ((c16 ^ (row & 7)) << 4));
  };

  const int T = K >> 6;
  stageA(0, 0, 0); stageA(0, 1, 0);   // A(0): 4 loads
  stageB(0, 0);                       // B(0): 2 loads
  stageB(1, 64);                      // B(1): 2 loads

  bf16x8 bfr[2][2];
  for (int w = 0; w < T; ++w) {
    const int c = w & 1;
    const int k1 = (w + 1) << 6, k2 = (w + 2) << 6;
#pragma unroll
    for (int p = 0; p < 2; ++p) {
      bf16x8 af[2][4];
      if (p == 0) {
        if (w + 1 < T) { ASM_VMCNT(2); } else { ASM_VMCNT(0); }
        bar_raw();
#pragma unroll
        for (int kk = 0; kk < 2; ++kk)
#pragma unroll
          for (int nf = 0; nf < 2; ++nf)
            bfr[kk][nf] = lreadB(c, wn + nf * 16 + lr, kk * 4 + lg);
      }
#pragma unroll
      for (int kk = 0; kk < 2; ++kk)
#pragma unroll
        for (int mf = 0; mf < 4; ++mf)
          af[kk][mf] = lreadA(c, ah, (4 * p + mf) * 16 + lr, kk * 4 + lg);
      if (p == 0 && w + 1 < T) { stageA(c ^ 1, 0, k1); stageA(c ^ 1, 1, k1); }
      if (p == 1 && w + 2 < T) stageB(c, k2);
      bar_raw();
      asm volatile("s_waitcnt lgkmcnt(0)" ::: "memory");
      __builtin_amdgcn_sched_barrier(0);
      __builtin_amdgcn_s_setprio(1);
#pragma unroll
      for (int kk = 0; kk < 2; ++kk)
#pragma unroll
        for (int mf = 0; mf < 4; ++mf)
#pragma unroll
          for (int nf = 0; nf < 2; ++nf)
            acc[4 * p + mf][nf] = __builtin_amdgcn_mfma_f32_16x16x32_bf16(
                af[kk][mf], bfr[kk][nf], acc[4 * p + mf][nf], 0, 0, 0);
      __builtin_amdgcn_s_setprio(0);
      bar_raw();
    }
  }

#pragma unroll
  for (int mf = 0; mf < 8; ++mf) {
#pragma unroll
    for (int nf = 0; nf < 2; ++nf) {
      const int col = n0 + wn + nf * 16 + lr;
#pragma unroll
      for (int r = 0; r < 4; ++r) {
        const int row = m0 + wm + mf * 16 + lg * 4 + r;
        float val = acc[mf][nf][r];
        const long idx = (long)row * ldc + col;
        if constexpr (EPIF == 1) val += Ef[(long)row * lde + col];
        if constexpr (EPIF == 4) val += C[idx];
        C[idx] = val;
      }
    }
  }
}

// ---------------------------------------------------------------------------
// 128xBN GEMM (round-7 pipelined body): sc1/sc2/ctx only.
// ---------------------------------------------------------------------------
enum { EPI_NONE = 0, EPI_ADD = 1, EPI_OUTADD = 4, EPI_PASS1 = 6, EPI_PASS2 = 7 };

template <typename OutT, int EPI, bool AF32, int NF, bool CK>
__device__ __forceinline__ void gemm_body(
    const void* __restrict__ Ap, long sAo, long sAi, int lda,
    const bf16* __restrict__ Bp, long sBo, long sBi, int ldb,
    OutT* Cp, long sCo, long sCi, int ldc,
    const void* Ep, long sEo, long sEi, int lde,
    float scale, int Hdiv, int M, int N, int K) {
  constexpr int BN = 32 * NF;
  constexpr int ACH = 512;
  constexpr int BCH = BN * 4;
  static_assert((EPI != EPI_PASS1 && EPI != EPI_PASS2) || NF == 4, "pass NF=4");

  const int z = blockIdx.z;
  const int zo = z / Hdiv, zi = z % Hdiv;

  const bf16* A = nullptr;
  const float* Af = nullptr;
  if constexpr (AF32) Af = (const float*)Ap + zo * sAo + zi * sAi;
  else                A  = (const bf16*)Ap + zo * sAo + zi * sAi;
  const bf16* Bw = Bp + zo * sBo + zi * sBi;
  OutT* C = Cp + zo * sCo + zi * sCi;

  const int t = threadIdx.x;
  const int m0 = blockIdx.y * 128, n0 = blockIdx.x * BN;

  if constexpr (EPI == EPI_PASS1) {
    if (blockIdx.x > blockIdx.y) return;
  }
  if constexpr (EPI == EPI_PASS2) {
    if (blockIdx.x > blockIdx.y) {
      for (int e = t; e < 128 * 32; e += 256) {
        const int row = e >> 5, col = (e & 31) * 4;
        *(float4*)&C[(long)(m0 + row) * ldc + n0 + col] =
            make_float4(0.f, 0.f, 0.f, 0.f);
      }
      return;
    }
  }

  __shared__ __align__(16) bf16 lsA[2][128 * 32];
  __shared__ __align__(16) bf16 lsB[2][BN * 32];

  const int wave = t >> 6, lane = t & 63;
  const int wm = (wave >> 1) * 64, wn = (wave & 1) * (NF * 16);
  const int lr = lane & 15, lg = lane >> 4;

  f32x4 acc[4][NF] = {};

  auto stage = [&](int buf, int k0) {
    if constexpr (AF32) {
#pragma unroll
      for (int c = 0; c < 2; ++c) {
        const int id = c * 256 + t;
        const int row = id >> 2, col = (id & 3) * 8;
        const float* src = Af + (long)(m0 + row) * lda + k0 + col;
        const float4 u0 = *(const float4*)src;
        const float4 u1 = *(const float4*)(src + 4);
        bf16x8 wv;
        wv[0] = (bf16)u0.x; wv[1] = (bf16)u0.y; wv[2] = (bf16)u0.z; wv[3] = (bf16)u0.w;
        wv[4] = (bf16)u1.x; wv[5] = (bf16)u1.y; wv[6] = (bf16)u1.z; wv[7] = (bf16)u1.w;
        *(bf16x8*)&lsA[buf][id * 8] = wv;
        if (NF == 4 || c == 0)
          gload_lds16(Bw + (long)(n0 + row) * ldb + k0 + col, &lsB[buf][id * 8]);
      }
    } else {
#pragma unroll
      for (int c = 0; c < (ACH + BCH) / 256; ++c) {
        const int id = c * 256 + t;
        if (id < ACH) {
          const int row = id >> 2, col = (id & 3) * 8;
          gload_lds16(A + (long)(m0 + row) * lda + k0 + col, &lsA[buf][id * 8]);
        } else {
          const int fid = id - ACH;
          const int row = fid >> 2, col = (fid & 3) * 8;
          gload_lds16(Bw + (long)(n0 + row) * ldb + k0 + col, &lsB[buf][fid * 8]);
        }
      }
    }
  };

  auto compute = [&](int buf) {
    bf16x8 af[4], bfr[NF];
#pragma unroll
    for (int i = 0; i < 4; ++i)
      af[i] = *(const bf16x8*)&lsA[buf][(wm + i * 16 + lr) * 32 + lg * 8];
#pragma unroll
    for (int j = 0; j < NF; ++j)
      bfr[j] = *(const bf16x8*)&lsB[buf][(wn + j * 16 + lr) * 32 + lg * 8];
#pragma unroll
    for (int i = 0; i < 4; ++i)
#pragma unroll
      for (int j = 0; j < NF; ++j)
        acc[i][j] = __builtin_amdgcn_mfma_f32_16x16x32_bf16(af[i], bfr[j],
                                                            acc[i][j], 0, 0, 0);
  };

  const int Klim = CK ? (m0 + 128) : K;
  int cur = 0;

  if constexpr (AF32) {
    stage(0, 0);
    __syncthreads();
    for (int k0 = 0; k0 < Klim - 32; k0 += 32) {
      stage(cur ^ 1, k0 + 32);
      compute(cur);
      __syncthreads();
      cur ^= 1;
    }
    compute(cur);
  } else {
    stage(0, 0);
    for (int k0 = 0; k0 < Klim - 32; k0 += 32) {
      stage(cur ^ 1, k0 + 32);
      if constexpr (NF == 4) ASM_VMCNT(4); else ASM_VMCNT(3);
      bar_raw();
      compute(cur);
      bar_raw();
      cur ^= 1;
    }
    ASM_VMCNT(0);
    bar_raw();
    compute(cur);
  }

  if constexpr (EPI == EPI_PASS1) {
    float2* statsP = (float2*)Ep;
    const int half = wn >> 6, nt = blockIdx.x;
#pragma unroll
    for (int i = 0; i < 4; ++i) {
#pragma unroll
      for (int r = 0; r < 4; ++r) {
        const int rowg = m0 + wm + i * 16 + lg * 4 + r;
        float v[NF];
        float mx = -3.0e38f;
#pragma unroll
        for (int j = 0; j < NF; ++j) {
          const int colg = n0 + wn + j * 16 + lr;
          v[j] = acc[i][j][r] * scale + (colg > rowg ? -1.0e9f : 0.0f);
          mx = fmaxf(mx, v[j]);
        }
        for (int sh = 1; sh <= 8; sh <<= 1) mx = fmaxf(mx, __shfl_xor(mx, sh));
        float s = 0.f;
#pragma unroll
        for (int j = 0; j < NF; ++j) s += expf(v[j] - mx);
        for (int sh = 1; sh <= 8; sh <<= 1) s += __shfl_xor(s, sh);
        if (lr == 0)
          statsP[(((long)(z << 10) + rowg) << 4) + nt * 2 + half] =
              make_float2(mx, s);
      }
    }
  } else if constexpr (EPI == EPI_PASS2) {
    const float2* sm = (const float2*)Ep;
#pragma unroll
    for (int i = 0; i < 4; ++i) {
#pragma unroll
      for (int j = 0; j < NF; ++j) {
        const int colg = n0 + wn + j * 16 + lr;
#pragma unroll
        for (int r = 0; r < 4; ++r) {
          const int rowg = m0 + wm + i * 16 + lg * 4 + r;
          float p = 0.0f;
          if (colg <= rowg) {
            const float2 st = sm[(z << 10) + rowg];
            p = expf(acc[i][j][r] * scale - st.x) * st.y;
          }
          C[(long)rowg * ldc + colg] = (OutT)p;
        }
      }
    }
  } else {
#pragma unroll
    for (int i = 0; i < 4; ++i) {
#pragma unroll
      for (int j = 0; j < NF; ++j) {
        const int col = n0 + wn + j * 16 + lr;
#pragma unroll
        for (int r = 0; r < 4; ++r) {
          const int rowi = m0 + wm + i * 16 + lg * 4 + r;
          C[(long)rowi * ldc + col] = (OutT)(acc[i][j][r] * scale);
        }
      }
    }
  }
}

#define GEMM_ARGS                                                        \
  const void* __restrict__ Ap, long sAo, long sAi, int lda,              \
  const bf16* __restrict__ Bp, long sBo, long sBi, int ldb,              \
  void* Cp, long sCo, long sCi, int ldc,                                 \
  const void* Ep, long sEo, long sEi, int lde,                           \
  float scale, int Hdiv, int M, int N, int K
#define GEMM_PASS Ap, sAo, sAi, lda, Bp, sBo, sBi, ldb, (OUT_T*)Cp, sCo, \
  sCi, ldc, Ep, sEo, sEi, lde, scale, Hdiv, M, N, K

#define DEF_GEMM(NAME, OUT_TY, EPI_V, AF32_V, NF_V, CK_V)                \
  __global__ __launch_bounds__(256) void NAME(GEMM_ARGS) {               \
    using OUT_T = OUT_TY;                                                \
    gemm_body<OUT_T, EPI_V, AF32_V, NF_V, CK_V>(GEMM_PASS);              \
  }

DEF_GEMM(gemm_sc1, float, EPI_PASS1, false, 4, false)
DEF_GEMM(gemm_sc2, float, EPI_PASS2, false, 4, false)
DEF_GEMM(gemm_ctx, bf16,  EPI_NONE,  true,  2, true)

// ---------------------------------------------------------------------------
// Host launcher
// ---------------------------------------------------------------------------
extern "C" void kernel_launch(void* const* d_in, const int* in_sizes, int n_in,
                              void* d_out, int out_size, void* d_ws,
                              size_t ws_size, hipStream_t stream) {
  (void)in_sizes; (void)n_in; (void)out_size; (void)ws_size;

  const float* hidden = (const float*)d_in[0];
  const float* cosb   = (const float*)d_in[2];
  const float* sinb   = (const float*)d_in[3];
  const float* q_w    = (const float*)d_in[4];
  const float* k_w    = (const float*)d_in[5];
  const float* v_w    = (const float*)d_in[6];
  const float* o_w    = (const float*)d_in[7];
  const float* gate_w = (const float*)d_in[8];
  const float* up_w   = (const float*)d_in[9];
  const float* down_w = (const float*)d_in[10];
  const float* ln1    = (const float*)d_in[11];
  const float* ln2    = (const float*)d_in[12];

  float* out  = (float*)d_out;             // (B,L,D): h1 then final
  float* attn = out + (long)kB * kL * kD;  // (B,H,L,L)

  // workspace layout (bf16 elements), ~201 MB
  bf16* wsb = (bf16*)d_ws;
  long off = 0;
  bf16* WQKV = wsb + off; off += 3L * kD * kD;         // q,k,v weights stacked
  bf16* WO   = wsb + off; off += (long)kD * kD;
  bf16* WBIG = wsb + off; off += (long)kI * kD;        // gate/up/down JIT
  bf16* HBF  = wsb + off; off += (long)kB * kL * kD;   // h/stats/ctx/DPART
  bf16* QKV  = wsb + off; off += (long)kB * kL * kQKV; // fused qkv; later h2
  bf16* GBUF = wsb + off; off += (long)kB * kL * kI;   // vT, then gate/mlp

  float2* STATS_P = (float2*)HBF;                      // 8 MB
  float2* STATS_M = STATS_P + (64L * 1024 * 16);       // 512 KB
  // DPART (33.5 MB f32) spans HBF (16.8 MB) + front of QKV (H2 region);
  // written at step 14 when both ctx-output (HBF) and H2 are dead.
  float*  DPART   = (float*)HBF;

  const long DD = (long)kD * kD;
  const long ID = (long)kI * kD;
  const int  ML = kB * kL;  // 4096

  // 1. cast attention weights (q,k,v stacked -> WQKV)
  cast_f32_bf16_kernel<<<dim3((int)(DD / 1024)), 256, 0, stream>>>(q_w, WQKV, DD);
  cast_f32_bf16_kernel<<<dim3((int)(DD / 1024)), 256, 0, stream>>>(k_w, WQKV + DD, DD);
  cast_f32_bf16_kernel<<<dim3((int)(DD / 1024)), 256, 0, stream>>>(v_w, WQKV + 2 * DD, DD);
  cast_f32_bf16_kernel<<<dim3((int)(DD / 1024)), 256, 0, stream>>>(o_w, WO, DD);

  // 2. rmsnorm1: hidden -> HBF (bf16)
  rmsnorm_kernel<<<ML, 256, 0, stream>>>(hidden, ln1, HBF);

  // 3. fused qkv projection (8-phase 256^2)
  gemm8p<0><<<dim3(ML / 256, kQKV / 256), 512, 0, stream>>>(
      HBF, kD, WQKV, kD, QKV, kQKV, nullptr, 0, kD);

  // 4. RoPE in-place on q,k
  rope_kernel<<<ML, 256, 0, stream>>>(QKV, cosb, sinb);

  // 5. v -> vT (B,H,DH,L) into GBUF
  transpose_v_kernel<<<dim3(kL / 32, kDH / 32, kB * kH), 256, 0, stream>>>(QKV, GBUF);

  // 6. scores pass 1: per-(row, ntile, half) max & sumexp (lower tiles only)
  gemm_sc1<<<dim3(kL / 128, kL / 128, kB * kH), 256, 0, stream>>>(
      QKV, (long)kL * kQKV, kDH, kQKV,
      QKV + kD, (long)kL * kQKV, kDH, kQKV,
      attn, (long)kH * kL * kL, (long)kL * kL, kL,
      STATS_P, 0, 0, 0,
      kScoreScale, kH, kL, kL, kDH);

  // 7. merge LSE stats -> per-row (max, 1/sum)
  merge_stats_kernel<<<256, 256, 0, stream>>>(STATS_P, STATS_M);

  // 8. scores pass 2: write softmaxed probs (upper tiles exact zero)
  gemm_sc2<<<dim3(kL / 128, kL / 128, kB * kH), 256, 0, stream>>>(
      QKV, (long)kL * kQKV, kDH, kQKV,
      QKV + kD, (long)kL * kQKV, kDH, kQKV,
      attn, (long)kH * kL * kL, (long)kL * kL, kL,
      STATS_M, 0, 0, 0,
      kScoreScale, kH, kL, kL, kDH);

  // 9. ctx = probs @ vT^T (A f32, causal K-limit) -> HBF
  gemm_ctx<<<dim3(kDH / 64, kL / 128, kB * kH), 256, 0, stream>>>(
      attn, (long)kH * kL * kL, (long)kL * kL, kL,
      GBUF, (long)kH * kDH * kL, (long)kDH * kL, kL,
      HBF, (long)kL * kD, kDH, kD,
      nullptr, 0, 0, 0, 1.0f, kH, kL, kDH, kL);

  // 10. h1 = hidden + ctx @ o_w^T -> out (2-phase 256x128, f32)
  gemm8pN128<1><<<dim3(ML / 256, kD / 128), 512, 0, stream>>>(
      HBF, kD, WO, kD, out, kD, hidden, kD, kD);

  // 11. rmsnorm2: h1 -> QKV region (h2 bf16, compact ld=kD)
  bf16* H2 = QKV;
  rmsnorm_kernel<<<ML, 256, 0, stream>>>(out, ln2, H2);

  // 12. gate = h2 @ gate_w^T -> GBUF (8-phase)
  cast_f32_bf16_kernel<<<dim3((int)(ID / 1024)), 256, 0, stream>>>(gate_w, WBIG, ID);
  gemm8p<0><<<dim3(ML / 256, kI / 256), 512, 0, stream>>>(
      H2, kD, WBIG, kD, GBUF, kI, nullptr, 0, kD);

  // 13. mlp = silu(gate) * (h2 @ up_w^T) -> GBUF in-place (8-phase)
  cast_f32_bf16_kernel<<<dim3((int)(ID / 1024)), 256, 0, stream>>>(up_w, WBIG, ID);
  gemm8p<3><<<dim3(ML / 256, kI / 256), 512, 0, stream>>>(
      H2, kD, WBIG, kD, GBUF, kI, GBUF, kI, kD);

  // 14. down via 256^2 8-phase split-K x2 (256 blocks = 1/CU, all CUs busy):
  //     z=0: out = h1 + mlp[:,:4096] @ W[:,:4096]^T
  //     z=1: DPART = mlp[:,4096:] @ W[:,4096:]^T
  cast_f32_bf16_kernel<<<dim3((int)(ID / 1024)), 256, 0, stream>>>(down_w, WBIG, ID);
  gemm8pF<<<dim3(ML / 256, kD / 256, 2), 512, 0, stream>>>(
      GBUF, kI, WBIG, kI, out, kD, DPART, kI / 2);

  // 15. out += DPART
  add_inplace_kernel<<<2048, 256, 0, stream>>>(out, DPART, (long)ML * kD);
}

// Round 16
// 969.227 us; speedup vs baseline: 1.0418x; 1.0418x over previous
//
#include <hip/hip_runtime.h>

// ---------------------------------------------------------------------------
// LlamaDecoderLayer forward on MI355X (gfx950).
// B=4, L=1024, D=2048, H=16, I=8192, DH=128.
// Outputs (f32): out (B,L,D) then attn (B,H,L,L), concatenated in d_out.
// ---------------------------------------------------------------------------

typedef __bf16 bf16;
typedef __bf16 bf16x8 __attribute__((ext_vector_type(8)));
typedef __bf16 bf16x4 __attribute__((ext_vector_type(4)));
typedef float  f32x4  __attribute__((ext_vector_type(4)));

constexpr int   kB  = 4;
constexpr int   kL  = 1024;
constexpr int   kD  = 2048;
constexpr int   kH  = 16;
constexpr int   kI  = 8192;
constexpr int   kDH = 128;
constexpr int   kQKV = 3 * kD;  // 6144
constexpr float kEps = 1e-6f;
constexpr float kScoreScale = 0.08838834764831845f; // 1/sqrt(128)

typedef __attribute__((address_space(1))) void gvoid_t;
typedef __attribute__((address_space(3))) void lvoid_t;

__device__ __forceinline__ void gload_lds16(const void* g, void* l) {
  __builtin_amdgcn_global_load_lds((gvoid_t*)g, (lvoid_t*)l, 16, 0, 0);
}

#define ASM_VMCNT(n) asm volatile("s_waitcnt vmcnt(" #n ")" ::: "memory")

__device__ __forceinline__ void bar_raw() {
  asm volatile("" ::: "memory");
  __builtin_amdgcn_s_barrier();
  asm volatile("" ::: "memory");
}

// ---------------------------------------------------------------------------
// f32 -> bf16 cast (vectorized). n must be a multiple of 4.
// ---------------------------------------------------------------------------
__global__ __launch_bounds__(256) void cast_f32_bf16_kernel(
    const float* __restrict__ x, bf16* __restrict__ y, long n) {
  long i = ((long)blockIdx.x * 256 + threadIdx.x) * 4;
  long stride = (long)gridDim.x * 256 * 4;
  for (; i < n; i += stride) {
    const float4 v = *reinterpret_cast<const float4*>(x + i);
    bf16x4 o;
    o[0] = (bf16)v.x; o[1] = (bf16)v.y; o[2] = (bf16)v.z; o[3] = (bf16)v.w;
    *reinterpret_cast<bf16x4*>(y + i) = o;
  }
}

// ---------------------------------------------------------------------------
// RMSNorm: one block per row of D=2048 f32; writes bf16 (row stride kD).
// ---------------------------------------------------------------------------
__global__ __launch_bounds__(256) void rmsnorm_kernel(
    const float* __restrict__ x, const float* __restrict__ w,
    bf16* __restrict__ out) {
  const long row = blockIdx.x;
  const float* xr = x + row * (long)kD;
  bf16* orow = out + row * (long)kD;
  const int t = threadIdx.x;

  float4 v0 = *(const float4*)(xr + t * 8);
  float4 v1 = *(const float4*)(xr + t * 8 + 4);
  float ss = v0.x * v0.x + v0.y * v0.y + v0.z * v0.z + v0.w * v0.w +
             v1.x * v1.x + v1.y * v1.y + v1.z * v1.z + v1.w * v1.w;

  __shared__ float red[4];
  for (int off = 32; off > 0; off >>= 1) ss += __shfl_down(ss, off);
  if ((t & 63) == 0) red[t >> 6] = ss;
  __syncthreads();
  const float tot = red[0] + red[1] + red[2] + red[3];
  const float rs = rsqrtf(tot / (float)kD + kEps);

  float4 w0 = *(const float4*)(w + t * 8);
  float4 w1 = *(const float4*)(w + t * 8 + 4);
  bf16x8 o;
  o[0] = (bf16)(v0.x * rs * w0.x); o[1] = (bf16)(v0.y * rs * w0.y);
  o[2] = (bf16)(v0.z * rs * w0.z); o[3] = (bf16)(v0.w * rs * w0.w);
  o[4] = (bf16)(v1.x * rs * w1.x); o[5] = (bf16)(v1.y * rs * w1.y);
  o[6] = (bf16)(v1.z * rs * w1.z); o[7] = (bf16)(v1.w * rs * w1.w);
  *(bf16x8*)(orow + t * 8) = o;
}

// ---------------------------------------------------------------------------
// RoPE in-place on qkv buffer (bf16, rows = B*L, ld = 6144).
// ---------------------------------------------------------------------------
__global__ __launch_bounds__(256) void rope_kernel(
    bf16* __restrict__ qkv, const float* __restrict__ cosb,
    const float* __restrict__ sinb) {
  const long row = blockIdx.x;  // b*L + l
  const float* cr = cosb + row * (long)kDH;
  const float* sr = sinb + row * (long)kDH;
  bf16* qr = qkv + row * (long)kQKV;
  bf16* kr = qr + kD;
  const int t = threadIdx.x;
#pragma unroll
  for (int it = 0; it < 4; ++it) {
    const int p = it * 256 + t;  // 0..1023 pair index
    const int h = p >> 6, i = p & 63;
    const int i0 = h * kDH + i, i1 = i0 + 64;
    const float c0 = cr[i], s0 = sr[i], c1 = cr[i + 64], s1 = sr[i + 64];
    const float q0 = (float)qr[i0], q1 = (float)qr[i1];
    qr[i0] = (bf16)(q0 * c0 - q1 * s0);
    qr[i1] = (bf16)(q1 * c1 + q0 * s1);
    const float k0 = (float)kr[i0], k1 = (float)kr[i1];
    kr[i0] = (bf16)(k0 * c0 - k1 * s0);
    kr[i1] = (bf16)(k1 * c1 + k0 * s1);
  }
}

// ---------------------------------------------------------------------------
// v (rows B*L, ld 6144, col offset 4096) -> vT (B,H,DH,L) bf16
// ---------------------------------------------------------------------------
__global__ __launch_bounds__(256) void transpose_v_kernel(
    const bf16* __restrict__ qkv, bf16* __restrict__ vT) {
  __shared__ bf16 tile[32][33];
  const int z = blockIdx.z, b = z / kH, h = z % kH;
  const bf16* src = qkv + (long)b * kL * kQKV + 2 * kD + h * kDH; // [l][d]
  bf16* dst = vT + (long)z * kDH * kL;                            // [d][l]
  const int l0 = blockIdx.x * 32, d0 = blockIdx.y * 32;
  const int tx = threadIdx.x & 31, ty = threadIdx.x >> 5;
  for (int r = ty; r < 32; r += 8)
    tile[r][tx] = src[(long)(l0 + r) * kQKV + d0 + tx];
  __syncthreads();
  for (int r = ty; r < 32; r += 8)
    dst[(long)(d0 + r) * kL + l0 + tx] = tile[tx][r];
}

// ---------------------------------------------------------------------------
// LSE merge: per-row (max, 1/sum) from per-(row, ntile, half) partials.
// ---------------------------------------------------------------------------
__global__ __launch_bounds__(256) void merge_stats_kernel(
    const float2* __restrict__ sp, float2* __restrict__ sm) {
  const int idx = blockIdx.x * 256 + threadIdx.x;  // bh*1024 + row
  const int row = idx & 1023;
  const int n = ((row >> 7) + 1) * 2;
  const float2* p = sp + ((long)idx << 4);
  float M = -3.0e38f;
  for (int i = 0; i < n; ++i) M = fmaxf(M, p[i].x);
  float S = 0.f;
  for (int i = 0; i < n; ++i) S += p[i].y * expf(p[i].x - M);
  sm[idx] = make_float2(M, 1.0f / S);
}

// ---------------------------------------------------------------------------
// 8-PHASE 256x256 GEMM (verified round 11). BK=64, 512 thr / 8 waves.
// Used for qkv only now.
// ---------------------------------------------------------------------------
template <int EPI>
__global__ __launch_bounds__(512) void gemm8p(
    const bf16* __restrict__ A, int lda, const bf16* __restrict__ B, int ldb,
    bf16* __restrict__ C, int ldc, const bf16* __restrict__ Ep, int lde,
    int K) {
  __shared__ __align__(16) bf16 ls[2][2][2][128 * 64];
  const int t = threadIdx.x;
  const int m0 = blockIdx.x * 256, n0 = blockIdx.y * 256;  // m fastest
  const int wave = t >> 6, lane = t & 63;
  const int ah = wave >> 2;              // A half this wave consumes
  const int wm = ah * 128;
  const int wn = (wave & 3) * 64;
  const int bh = wn >> 7;                // B half this wave consumes
  const int wnr = wn & 127;              // row base within B half
  const int lr = lane & 15, lg = lane >> 4;

  f32x4 acc[8][4] = {};

  auto stageHalf = [&](int b, int O, int h, int k0) {
    const bf16* S = O ? B : A;
    const int ld = O ? ldb : lda;
    const int base = O ? n0 : m0;
#pragma unroll
    for (int cc = 0; cc < 2; ++cc) {
      const int id = cc * 512 + t;       // 0..1023 16B chunks
      const int row = id >> 3, cS = id & 7;
      const int cG = cS ^ (row & 7);     // inverse swizzle on SOURCE
      gload_lds16(S + (long)(base + h * 128 + row) * ld + k0 + cG * 8,
                  (char*)&ls[b][O][h][0] + id * 16);
    }
  };

  auto lread = [&](int b, int O, int h, int row, int c16) {
    return *(const bf16x8*)((const char*)&ls[b][O][h][0] + row * 128 +
                            ((c16 ^ (row & 7)) << 4));
  };

  const int T = K >> 6;
  stageHalf(0, 0, 0, 0); stageHalf(0, 0, 1, 0);
  stageHalf(0, 1, 0, 0); stageHalf(0, 1, 1, 0);
  stageHalf(1, 1, 0, 64); stageHalf(1, 1, 1, 64);

  bf16x8 bfr[2][4];

  for (int w = 0; w < T; ++w) {
    const int c = w & 1;
    const int k1 = (w + 1) << 6, k2 = (w + 2) << 6;
#pragma unroll
    for (int p = 0; p < 4; ++p) {
      bf16x8 af[2][2];
      if (p == 0) {
        if (w + 1 < T) { ASM_VMCNT(4); } else { ASM_VMCNT(0); }
        bar_raw();  // all waves' staging for window w landed
#pragma unroll
        for (int kk = 0; kk < 2; ++kk)
#pragma unroll
          for (int nf = 0; nf < 4; ++nf)
            bfr[kk][nf] = lread(c, 1, bh, wnr + nf * 16 + lr, kk * 4 + lg);
      }
#pragma unroll
      for (int kk = 0; kk < 2; ++kk)
#pragma unroll
        for (int mf = 0; mf < 2; ++mf)
          af[kk][mf] = lread(c, 0, ah, (2 * p + mf) * 16 + lr, kk * 4 + lg);
      if (p == 0 && w + 1 < T) stageHalf(c ^ 1, 0, 0, k1);
      if (p == 1 && w + 1 < T) stageHalf(c ^ 1, 0, 1, k1);
      if (p == 2 && w + 2 < T) stageHalf(c, 1, 0, k2);
      if (p == 3 && w + 2 < T) stageHalf(c, 1, 1, k2);
      bar_raw();
      asm volatile("s_waitcnt lgkmcnt(0)" ::: "memory");
      __builtin_amdgcn_sched_barrier(0);  // rule #18
      __builtin_amdgcn_s_setprio(1);
#pragma unroll
      for (int kk = 0; kk < 2; ++kk)
#pragma unroll
        for (int mf = 0; mf < 2; ++mf)
#pragma unroll
          for (int nf = 0; nf < 4; ++nf)
            acc[2 * p + mf][nf] = __builtin_amdgcn_mfma_f32_16x16x32_bf16(
                af[kk][mf], bfr[kk][nf], acc[2 * p + mf][nf], 0, 0, 0);
      __builtin_amdgcn_s_setprio(0);
      bar_raw();
    }
  }

#pragma unroll
  for (int mf = 0; mf < 8; ++mf) {
#pragma unroll
    for (int nf = 0; nf < 4; ++nf) {
      const int col = n0 + wn + nf * 16 + lr;
#pragma unroll
      for (int r = 0; r < 4; ++r) {
        const int row = m0 + wm + mf * 16 + lg * 4 + r;
        float val = acc[mf][nf][r];
        if constexpr (EPI == 3) {
          const float g = (float)Ep[(long)row * lde + col];
          val = (g / (1.0f + expf(-g))) * val;
        }
        C[(long)row * ldc + col] = (bf16)val;
      }
    }
  }
}

// ---------------------------------------------------------------------------
// FUSED MLP GEMM (round 16): mlp = silu(A@Bg^T) * (A@Bu^T), bf16 out.
// BM=256, BN=128 (same cols for gate & up), BK=64, 512 thr / 8 waves.
// LDS 128 KB: A dbuf 2x2x16KB + Bg dbuf 2x16KB + Bu dbuf 2x16KB.
// Per phase: 16 MFMA (8 gate + 8 up) SHARING the A fragments.
// Prefetch: p0/p1 -> A halves (w+1), p2 -> Bg(w+2), p3 -> Bu(w+2).
// vmcnt ledger identical to gemm8p: steady vmcnt(4) leaves Bg/Bu(w+1) in
// flight (traced: prologue 12 loads; at w p0 outstanding =
// [Bg(w),Bu(w),A(w),Bg(w+1),Bu(w+1)] = 12 -> wait 8 oldest).
// ---------------------------------------------------------------------------
__global__ __launch_bounds__(512) void gemm8pMLP(
    const bf16* __restrict__ A, int lda,
    const bf16* __restrict__ Bg, const bf16* __restrict__ Bu, int ldb,
    bf16* __restrict__ C, int ldc, int K) {
  __shared__ __align__(16) bf16 lsA[2][2][128 * 64];
  __shared__ __align__(16) bf16 lsG[2][128 * 64];
  __shared__ __align__(16) bf16 lsU[2][128 * 64];
  const int t = threadIdx.x;
  const int m0 = blockIdx.x * 256, n0 = blockIdx.y * 128;  // m fastest
  const int wave = t >> 6, lane = t & 63;
  const int ah = wave >> 2;
  const int wm = ah * 128;
  const int wn = (wave & 3) * 32;
  const int lr = lane & 15, lg = lane >> 4;

  f32x4 aG[8][2] = {}, aU[8][2] = {};

  auto stageA = [&](int b, int h, int k0) {
#pragma unroll
    for (int cc = 0; cc < 2; ++cc) {
      const int id = cc * 512 + t;
      const int row = id >> 3, cS = id & 7;
      const int cG = cS ^ (row & 7);
      gload_lds16(A + (long)(m0 + h * 128 + row) * lda + k0 + cG * 8,
                  (char*)&lsA[b][h][0] + id * 16);
    }
  };
  auto stageW = [&](bf16* dst, const bf16* B, int k0) {
#pragma unroll
    for (int cc = 0; cc < 2; ++cc) {
      const int id = cc * 512 + t;
      const int row = id >> 3, cS = id & 7;
      const int cG = cS ^ (row & 7);
      gload_lds16(B + (long)(n0 + row) * ldb + k0 + cG * 8,
                  (char*)dst + id * 16);
    }
  };
  auto lread = [&](const bf16* base, int row, int c16) {
    return *(const bf16x8*)((const char*)base + row * 128 +
                            ((c16 ^ (row & 7)) << 4));
  };

  const int T = K >> 6;
  // prologue: A(0) 4, Bg(0) 2, Bu(0) 2, Bg(1) 2, Bu(1) 2 = 12 loads
  stageA(0, 0, 0); stageA(0, 1, 0);
  stageW(lsG[0], Bg, 0); stageW(lsU[0], Bu, 0);
  stageW(lsG[1], Bg, 64); stageW(lsU[1], Bu, 64);

  bf16x8 bG[2][2], bU[2][2];
  for (int w = 0; w < T; ++w) {
    const int c = w & 1;
    const int k1 = (w + 1) << 6, k2 = (w + 2) << 6;
#pragma unroll
    for (int p = 0; p < 4; ++p) {
      bf16x8 af[2][2];
      if (p == 0) {
        if (w + 1 < T) { ASM_VMCNT(4); } else { ASM_VMCNT(0); }
        bar_raw();
#pragma unroll
        for (int kk = 0; kk < 2; ++kk)
#pragma unroll
          for (int nf = 0; nf < 2; ++nf) {
            bG[kk][nf] = lread(lsG[c], wn + nf * 16 + lr, kk * 4 + lg);
            bU[kk][nf] = lread(lsU[c], wn + nf * 16 + lr, kk * 4 + lg);
          }
      }
#pragma unroll
      for (int kk = 0; kk < 2; ++kk)
#pragma unroll
        for (int mf = 0; mf < 2; ++mf)
          af[kk][mf] = lread(lsA[c][ah], (2 * p + mf) * 16 + lr, kk * 4 + lg);
      if (p == 0 && w + 1 < T) stageA(c ^ 1, 0, k1);
      if (p == 1 && w + 1 < T) stageA(c ^ 1, 1, k1);
      if (p == 2 && w + 2 < T) stageW(lsG[c], Bg, k2);
      if (p == 3 && w + 2 < T) stageW(lsU[c], Bu, k2);
      bar_raw();
      asm volatile("s_waitcnt lgkmcnt(0)" ::: "memory");
      __builtin_amdgcn_sched_barrier(0);
      __builtin_amdgcn_s_setprio(1);
#pragma unroll
      for (int kk = 0; kk < 2; ++kk)
#pragma unroll
        for (int mf = 0; mf < 2; ++mf)
#pragma unroll
          for (int nf = 0; nf < 2; ++nf) {
            aG[2 * p + mf][nf] = __builtin_amdgcn_mfma_f32_16x16x32_bf16(
                af[kk][mf], bG[kk][nf], aG[2 * p + mf][nf], 0, 0, 0);
            aU[2 * p + mf][nf] = __builtin_amdgcn_mfma_f32_16x16x32_bf16(
                af[kk][mf], bU[kk][nf], aU[2 * p + mf][nf], 0, 0, 0);
          }
      __builtin_amdgcn_s_setprio(0);
      bar_raw();
    }
  }

#pragma unroll
  for (int mf = 0; mf < 8; ++mf) {
#pragma unroll
    for (int nf = 0; nf < 2; ++nf) {
      const int col = n0 + wn + nf * 16 + lr;
#pragma unroll
      for (int r = 0; r < 4; ++r) {
        const int row = m0 + wm + mf * 16 + lg * 4 + r;
        const float g = aG[mf][nf][r], u = aU[mf][nf][r];
        C[(long)row * ldc + col] = (bf16)((g / (1.0f + expf(-g))) * u);
      }
    }
  }
}

// ---------------------------------------------------------------------------
// 2-PHASE-PER-WINDOW 256x128 GEMM, f32 output (down / oproj; grid 16x16).
// Round-13 verified. EPIF: 1 = +E (oproj), 4 = +C in-place (down).
// ---------------------------------------------------------------------------
template <int EPIF>
__global__ __launch_bounds__(512) void gemm8pN128(
    const bf16* __restrict__ A, int lda, const bf16* __restrict__ B, int ldb,
    float* __restrict__ C, int ldc, const float* __restrict__ Ef, int lde,
    int K) {
  __shared__ __align__(16) bf16 lsA[2][2][128 * 64];
  __shared__ __align__(16) bf16 lsB[2][128 * 64];
  const int t = threadIdx.x;
  const int m0 = blockIdx.x * 256, n0 = blockIdx.y * 128;  // m fastest
  const int wave = t >> 6, lane = t & 63;
  const int ah = wave >> 2;
  const int wm = ah * 128;
  const int wn = (wave & 3) * 32;
  const int lr = lane & 15, lg = lane >> 4;

  f32x4 acc[8][2] = {};

  auto stageA = [&](int b, int h, int k0) {
#pragma unroll
    for (int cc = 0; cc < 2; ++cc) {
      const int id = cc * 512 + t;
      const int row = id >> 3, cS = id & 7;
      const int cG = cS ^ (row & 7);
      gload_lds16(A + (long)(m0 + h * 128 + row) * lda + k0 + cG * 8,
                  (char*)&lsA[b][h][0] + id * 16);
    }
  };
  auto stageB = [&](int b, int k0) {
#pragma unroll
    for (int cc = 0; cc < 2; ++cc) {
      const int id = cc * 512 + t;
      const int row = id >> 3, cS = id & 7;
      const int cG = cS ^ (row & 7);
      gload_lds16(B + (long)(n0 + row) * ldb + k0 + cG * 8,
                  (char*)&lsB[b][0] + id * 16);
    }
  };
  auto lreadA = [&](int b, int h, int row, int c16) {
    return *(const bf16x8*)((const char*)&lsA[b][h][0] + row * 128 +
                            ((c16 ^ (row & 7)) << 4));
  };
  auto lreadB = [&](int b, int row, int c16) {
    return *(const bf16x8*)((const char*)&lsB[b][0] + row * 128 +
                            ((c16 ^ (row & 7)) << 4));
  };

  const int T = K >> 6;
  stageA(0, 0, 0); stageA(0, 1, 0);   // A(0): 4 loads
  stageB(0, 0);                       // B(0): 2 loads
  stageB(1, 64);                      // B(1): 2 loads

  bf16x8 bfr[2][2];
  for (int w = 0; w < T; ++w) {
    const int c = w & 1;
    const int k1 = (w + 1) << 6, k2 = (w + 2) << 6;
#pragma unroll
    for (int p = 0; p < 2; ++p) {
      bf16x8 af[2][4];
      if (p == 0) {
        if (w + 1 < T) { ASM_VMCNT(2); } else { ASM_VMCNT(0); }
        bar_raw();
#pragma unroll
        for (int kk = 0; kk < 2; ++kk)
#pragma unroll
          for (int nf = 0; nf < 2; ++nf)
            bfr[kk][nf] = lreadB(c, wn + nf * 16 + lr, kk * 4 + lg);
      }
#pragma unroll
      for (int kk = 0; kk < 2; ++kk)
#pragma unroll
        for (int mf = 0; mf < 4; ++mf)
          af[kk][mf] = lreadA(c, ah, (4 * p + mf) * 16 + lr, kk * 4 + lg);
      if (p == 0 && w + 1 < T) { stageA(c ^ 1, 0, k1); stageA(c ^ 1, 1, k1); }
      if (p == 1 && w + 2 < T) stageB(c, k2);
      bar_raw();
      asm volatile("s_waitcnt lgkmcnt(0)" ::: "memory");
      __builtin_amdgcn_sched_barrier(0);
      __builtin_amdgcn_s_setprio(1);
#pragma unroll
      for (int kk = 0; kk < 2; ++kk)
#pragma unroll
        for (int mf = 0; mf < 4; ++mf)
#pragma unroll
          for (int nf = 0; nf < 2; ++nf)
            acc[4 * p + mf][nf] = __builtin_amdgcn_mfma_f32_16x16x32_bf16(
                af[kk][mf], bfr[kk][nf], acc[4 * p + mf][nf], 0, 0, 0);
      __builtin_amdgcn_s_setprio(0);
      bar_raw();
    }
  }

#pragma unroll
  for (int mf = 0; mf < 8; ++mf) {
#pragma unroll
    for (int nf = 0; nf < 2; ++nf) {
      const int col = n0 + wn + nf * 16 + lr;
#pragma unroll
      for (int r = 0; r < 4; ++r) {
        const int row = m0 + wm + mf * 16 + lg * 4 + r;
        float val = acc[mf][nf][r];
        const long idx = (long)row * ldc + col;
        if constexpr (EPIF == 1) val += Ef[(long)row * lde + col];
        if constexpr (EPIF == 4) val += C[idx];
        C[idx] = val;
      }
    }
  }
}

// ---------------------------------------------------------------------------
// 128xBN GEMM (round-7 pipelined body): sc1/sc2/ctx only.
// ---------------------------------------------------------------------------
enum { EPI_NONE = 0, EPI_ADD = 1, EPI_OUTADD = 4, EPI_PASS1 = 6, EPI_PASS2 = 7 };

template <typename OutT, int EPI, bool AF32, int NF, bool CK>
__device__ __forceinline__ void gemm_body(
    const void* __restrict__ Ap, long sAo, long sAi, int lda,
    const bf16* __restrict__ Bp, long sBo, long sBi, int ldb,
    OutT* Cp, long sCo, long sCi, int ldc,
    const void* Ep, long sEo, long sEi, int lde,
    float scale, int Hdiv, int M, int N, int K) {
  constexpr int BN = 32 * NF;
  constexpr int ACH = 512;
  constexpr int BCH = BN * 4;
  static_assert((EPI != EPI_PASS1 && EPI != EPI_PASS2) || NF == 4, "pass NF=4");

  const int z = blockIdx.z;
  const int zo = z / Hdiv, zi = z % Hdiv;

  const bf16* A = nullptr;
  const float* Af = nullptr;
  if constexpr (AF32) Af = (const float*)Ap + zo * sAo + zi * sAi;
  else                A  = (const bf16*)Ap + zo * sAo + zi * sAi;
  const bf16* Bw = Bp + zo * sBo + zi * sBi;
  OutT* C = Cp + zo * sCo + zi * sCi;

  const int t = threadIdx.x;
  const int m0 = blockIdx.y * 128, n0 = blockIdx.x * BN;

  if constexpr (EPI == EPI_PASS1) {
    if (blockIdx.x > blockIdx.y) return;
  }
  if constexpr (EPI == EPI_PASS2) {
    if (blockIdx.x > blockIdx.y) {
      for (int e = t; e < 128 * 32; e += 256) {
        const int row = e >> 5, col = (e & 31) * 4;
        *(float4*)&C[(long)(m0 + row) * ldc + n0 + col] =
            make_float4(0.f, 0.f, 0.f, 0.f);
      }
      return;
    }
  }

  __shared__ __align__(16) bf16 lsA[2][128 * 32];
  __shared__ __align__(16) bf16 lsB[2][BN * 32];

  const int wave = t >> 6, lane = t & 63;
  const int wm = (wave >> 1) * 64, wn = (wave & 1) * (NF * 16);
  const int lr = lane & 15, lg = lane >> 4;

  f32x4 acc[4][NF] = {};

  auto stage = [&](int buf, int k0) {
    if constexpr (AF32) {
#pragma unroll
      for (int c = 0; c < 2; ++c) {
        const int id = c * 256 + t;
        const int row = id >> 2, col = (id & 3) * 8;
        const float* src = Af + (long)(m0 + row) * lda + k0 + col;
        const float4 u0 = *(const float4*)src;
        const float4 u1 = *(const float4*)(src + 4);
        bf16x8 wv;
        wv[0] = (bf16)u0.x; wv[1] = (bf16)u0.y; wv[2] = (bf16)u0.z; wv[3] = (bf16)u0.w;
        wv[4] = (bf16)u1.x; wv[5] = (bf16)u1.y; wv[6] = (bf16)u1.z; wv[7] = (bf16)u1.w;
        *(bf16x8*)&lsA[buf][id * 8] = wv;
        if (NF == 4 || c == 0)
          gload_lds16(Bw + (long)(n0 + row) * ldb + k0 + col, &lsB[buf][id * 8]);
      }
    } else {
#pragma unroll
      for (int c = 0; c < (ACH + BCH) / 256; ++c) {
        const int id = c * 256 + t;
        if (id < ACH) {
          const int row = id >> 2, col = (id & 3) * 8;
          gload_lds16(A + (long)(m0 + row) * lda + k0 + col, &lsA[buf][id * 8]);
        } else {
          const int fid = id - ACH;
          const int row = fid >> 2, col = (fid & 3) * 8;
          gload_lds16(Bw + (long)(n0 + row) * ldb + k0 + col, &lsB[buf][fid * 8]);
        }
      }
    }
  };

  auto compute = [&](int buf) {
    bf16x8 af[4], bfr[NF];
#pragma unroll
    for (int i = 0; i < 4; ++i)
      af[i] = *(const bf16x8*)&lsA[buf][(wm + i * 16 + lr) * 32 + lg * 8];
#pragma unroll
    for (int j = 0; j < NF; ++j)
      bfr[j] = *(const bf16x8*)&lsB[buf][(wn + j * 16 + lr) * 32 + lg * 8];
#pragma unroll
    for (int i = 0; i < 4; ++i)
#pragma unroll
      for (int j = 0; j < NF; ++j)
        acc[i][j] = __builtin_amdgcn_mfma_f32_16x16x32_bf16(af[i], bfr[j],
                                                            acc[i][j], 0, 0, 0);
  };

  const int Klim = CK ? (m0 + 128) : K;
  int cur = 0;

  if constexpr (AF32) {
    stage(0, 0);
    __syncthreads();
    for (int k0 = 0; k0 < Klim - 32; k0 += 32) {
      stage(cur ^ 1, k0 + 32);
      compute(cur);
      __syncthreads();
      cur ^= 1;
    }
    compute(cur);
  } else {
    stage(0, 0);
    for (int k0 = 0; k0 < Klim - 32; k0 += 32) {
      stage(cur ^ 1, k0 + 32);
      if constexpr (NF == 4) ASM_VMCNT(4); else ASM_VMCNT(3);
      bar_raw();
      compute(cur);
      bar_raw();
      cur ^= 1;
    }
    ASM_VMCNT(0);
    bar_raw();
    compute(cur);
  }

  if constexpr (EPI == EPI_PASS1) {
    float2* statsP = (float2*)Ep;
    const int half = wn >> 6, nt = blockIdx.x;
#pragma unroll
    for (int i = 0; i < 4; ++i) {
#pragma unroll
      for (int r = 0; r < 4; ++r) {
        const int rowg = m0 + wm + i * 16 + lg * 4 + r;
        float v[NF];
        float mx = -3.0e38f;
#pragma unroll
        for (int j = 0; j < NF; ++j) {
          const int colg = n0 + wn + j * 16 + lr;
          v[j] = acc[i][j][r] * scale + (colg > rowg ? -1.0e9f : 0.0f);
          mx = fmaxf(mx, v[j]);
        }
        for (int sh = 1; sh <= 8; sh <<= 1) mx = fmaxf(mx, __shfl_xor(mx, sh));
        float s = 0.f;
#pragma unroll
        for (int j = 0; j < NF; ++j) s += expf(v[j] - mx);
        for (int sh = 1; sh <= 8; sh <<= 1) s += __shfl_xor(s, sh);
        if (lr == 0)
          statsP[(((long)(z << 10) + rowg) << 4) + nt * 2 + half] =
              make_float2(mx, s);
      }
    }
  } else if constexpr (EPI == EPI_PASS2) {
    const float2* sm = (const float2*)Ep;
#pragma unroll
    for (int i = 0; i < 4; ++i) {
#pragma unroll
      for (int j = 0; j < NF; ++j) {
        const int colg = n0 + wn + j * 16 + lr;
#pragma unroll
        for (int r = 0; r < 4; ++r) {
          const int rowg = m0 + wm + i * 16 + lg * 4 + r;
          float p = 0.0f;
          if (colg <= rowg) {
            const float2 st = sm[(z << 10) + rowg];
            p = expf(acc[i][j][r] * scale - st.x) * st.y;
          }
          C[(long)rowg * ldc + colg] = (OutT)p;
        }
      }
    }
  } else {
#pragma unroll
    for (int i = 0; i < 4; ++i) {
#pragma unroll
      for (int j = 0; j < NF; ++j) {
        const int col = n0 + wn + j * 16 + lr;
#pragma unroll
        for (int r = 0; r < 4; ++r) {
          const int rowi = m0 + wm + i * 16 + lg * 4 + r;
          C[(long)rowi * ldc + col] = (OutT)(acc[i][j][r] * scale);
        }
      }
    }
  }
}

#define GEMM_ARGS                                                        \
  const void* __restrict__ Ap, long sAo, long sAi, int lda,              \
  const bf16* __restrict__ Bp, long sBo, long sBi, int ldb,              \
  void* Cp, long sCo, long sCi, int ldc,                                 \
  const void* Ep, long sEo, long sEi, int lde,                           \
  float scale, int Hdiv, int M, int N, int K
#define GEMM_PASS Ap, sAo, sAi, lda, Bp, sBo, sBi, ldb, (OUT_T*)Cp, sCo, \
  sCi, ldc, Ep, sEo, sEi, lde, scale, Hdiv, M, N, K

#define DEF_GEMM(NAME, OUT_TY, EPI_V, AF32_V, NF_V, CK_V)                \
  __global__ __launch_bounds__(256) void NAME(GEMM_ARGS) {               \
    using OUT_T = OUT_TY;                                                \
    gemm_body<OUT_T, EPI_V, AF32_V, NF_V, CK_V>(GEMM_PASS);              \
  }

DEF_GEMM(gemm_sc1, float, EPI_PASS1, false, 4, false)
DEF_GEMM(gemm_sc2, float, EPI_PASS2, false, 4, false)
DEF_GEMM(gemm_ctx, bf16,  EPI_NONE,  true,  2, true)

// ---------------------------------------------------------------------------
// Host launcher
// ---------------------------------------------------------------------------
extern "C" void kernel_launch(void* const* d_in, const int* in_sizes, int n_in,
                              void* d_out, int out_size, void* d_ws,
                              size_t ws_size, hipStream_t stream) {
  (void)in_sizes; (void)n_in; (void)out_size; (void)ws_size;

  const float* hidden = (const float*)d_in[0];
  const float* cosb   = (const float*)d_in[2];
  const float* sinb   = (const float*)d_in[3];
  const float* q_w    = (const float*)d_in[4];
  const float* k_w    = (const float*)d_in[5];
  const float* v_w    = (const float*)d_in[6];
  const float* o_w    = (const float*)d_in[7];
  const float* gate_w = (const float*)d_in[8];
  const float* up_w   = (const float*)d_in[9];
  const float* down_w = (const float*)d_in[10];
  const float* ln1    = (const float*)d_in[11];
  const float* ln2    = (const float*)d_in[12];

  float* out  = (float*)d_out;             // (B,L,D): h1 then final
  float* attn = out + (long)kB * kL * kD;  // (B,H,L,L)

  // workspace layout (bf16 elements), ~235 MB (round-9-proven size)
  bf16* wsb = (bf16*)d_ws;
  long off = 0;
  bf16* WQKV = wsb + off; off += 3L * kD * kD;         // q,k,v weights stacked
  bf16* WO   = wsb + off; off += (long)kD * kD;
  bf16* WG   = wsb + off; off += (long)kI * kD;        // gate (later down)
  bf16* WU   = wsb + off; off += (long)kI * kD;        // up
  bf16* HBF  = wsb + off; off += (long)kB * kL * kD;   // h (ln1) / stats / ctx
  bf16* QKV  = wsb + off; off += (long)kB * kL * kQKV; // fused qkv; later h2
  bf16* GBUF = wsb + off; off += (long)kB * kL * kI;   // vT, then mlp

  float2* STATS_P = (float2*)HBF;                      // 8 MB
  float2* STATS_M = STATS_P + (64L * 1024 * 16);       // 512 KB

  const long DD = (long)kD * kD;
  const long ID = (long)kI * kD;
  const int  ML = kB * kL;  // 4096

  // 1. cast attention weights (q,k,v stacked -> WQKV)
  cast_f32_bf16_kernel<<<dim3((int)(DD / 1024)), 256, 0, stream>>>(q_w, WQKV, DD);
  cast_f32_bf16_kernel<<<dim3((int)(DD / 1024)), 256, 0, stream>>>(k_w, WQKV + DD, DD);
  cast_f32_bf16_kernel<<<dim3((int)(DD / 1024)), 256, 0, stream>>>(v_w, WQKV + 2 * DD, DD);
  cast_f32_bf16_kernel<<<dim3((int)(DD / 1024)), 256, 0, stream>>>(o_w, WO, DD);

  // 2. rmsnorm1: hidden -> HBF (bf16)
  rmsnorm_kernel<<<ML, 256, 0, stream>>>(hidden, ln1, HBF);

  // 3. fused qkv projection (8-phase 256^2)
  gemm8p<0><<<dim3(ML / 256, kQKV / 256), 512, 0, stream>>>(
      HBF, kD, WQKV, kD, QKV, kQKV, nullptr, 0, kD);

  // 4. RoPE in-place on q,k
  rope_kernel<<<ML, 256, 0, stream>>>(QKV, cosb, sinb);

  // 5. v -> vT (B,H,DH,L) into GBUF
  transpose_v_kernel<<<dim3(kL / 32, kDH / 32, kB * kH), 256, 0, stream>>>(QKV, GBUF);

  // 6. scores pass 1: per-(row, ntile, half) max & sumexp (lower tiles only)
  gemm_sc1<<<dim3(kL / 128, kL / 128, kB * kH), 256, 0, stream>>>(
      QKV, (long)kL * kQKV, kDH, kQKV,
      QKV + kD, (long)kL * kQKV, kDH, kQKV,
      attn, (long)kH * kL * kL, (long)kL * kL, kL,
      STATS_P, 0, 0, 0,
      kScoreScale, kH, kL, kL, kDH);

  // 7. merge LSE stats -> per-row (max, 1/sum)
  merge_stats_kernel<<<256, 256, 0, stream>>>(STATS_P, STATS_M);

  // 8. scores pass 2: write softmaxed probs (upper tiles exact zero)
  gemm_sc2<<<dim3(kL / 128, kL / 128, kB * kH), 256, 0, stream>>>(
      QKV, (long)kL * kQKV, kDH, kQKV,
      QKV + kD, (long)kL * kQKV, kDH, kQKV,
      attn, (long)kH * kL * kL, (long)kL * kL, kL,
      STATS_M, 0, 0, 0,
      kScoreScale, kH, kL, kL, kDH);

  // 9. ctx = probs @ vT^T (A f32, causal K-limit) -> HBF
  gemm_ctx<<<dim3(kDH / 64, kL / 128, kB * kH), 256, 0, stream>>>(
      attn, (long)kH * kL * kL, (long)kL * kL, kL,
      GBUF, (long)kH * kDH * kL, (long)kDH * kL, kL,
      HBF, (long)kL * kD, kDH, kD,
      nullptr, 0, 0, 0, 1.0f, kH, kL, kDH, kL);

  // 10. h1 = hidden + ctx @ o_w^T -> out (2-phase 256x128, f32)
  gemm8pN128<1><<<dim3(ML / 256, kD / 128), 512, 0, stream>>>(
      HBF, kD, WO, kD, out, kD, hidden, kD, kD);

  // 11. rmsnorm2: h1 -> QKV region (h2 bf16, compact ld=kD)
  bf16* H2 = QKV;
  rmsnorm_kernel<<<ML, 256, 0, stream>>>(out, ln2, H2);

  // 12. fused mlp = silu(h2@gate^T) * (h2@up^T) -> GBUF (dual-B 8-phase)
  cast_f32_bf16_kernel<<<dim3((int)(ID / 1024)), 256, 0, stream>>>(gate_w, WG, ID);
  cast_f32_bf16_kernel<<<dim3((int)(ID / 1024)), 256, 0, stream>>>(up_w, WU, ID);
  gemm8pMLP<<<dim3(ML / 256, kI / 128), 512, 0, stream>>>(
      H2, kD, WG, WU, kD, GBUF, kI, kD);

  // 13. out = h1 + mlp @ down_w^T (2-phase 256x128, f32, in-place add)
  cast_f32_bf16_kernel<<<dim3((int)(ID / 1024)), 256, 0, stream>>>(down_w, WG, ID);
  gemm8pN128<4><<<dim3(ML / 256, kD / 128), 512, 0, stream>>>(
      GBUF, kI, WG, kI, out, kD, nullptr, 0, kI);
}